// Round 1
// baseline (566.095 us; speedup 1.0000x reference)
//
#include <hip/hip_runtime.h>

// MultiScaleTimeMixer: B=2048, T=128, C=128, scales {128, 64, 32}
// One block (256 thr, 4 waves) per batch. bf16 MFMA 16x16x32 everywhere.

typedef __attribute__((ext_vector_type(8))) short s16x8;
typedef __attribute__((ext_vector_type(4))) float f32x4;

#define XS_STRIDE 136   // 128 + 8 bf16 pad: rows 272 B (16B aligned), 2-way max bank alias

__device__ __forceinline__ unsigned short f2bf(float f){
  unsigned int u = __float_as_uint(f);
  u += 0x7FFFu + ((u >> 16) & 1u);          // RNE
  return (unsigned short)(u >> 16);
}
__device__ __forceinline__ float bf2f(unsigned short u){
  return __uint_as_float(((unsigned int)u) << 16);
}
__device__ __forceinline__ float hswish(float v){
  float c = fminf(fmaxf(v + 3.0f, 0.0f), 6.0f);
  return v * c * (1.0f / 6.0f);
}

// D[m][n] += A[m][k]*B[n][k] (B given row-major over n, i.e. B^T form).
// Arow: LDS ptr already offset to row (mbase+m16). Brow: global ptr already offset by m16*bstride.
template<int NT, int KT>
__device__ __forceinline__ void mm_lds_a(const unsigned short* Arow,
                                         const unsigned short* Brow,
                                         int bstride, f32x4* acc, int quad){
#pragma unroll
  for (int kt = 0; kt < KT; ++kt){
    s16x8 a = *(const s16x8*)(Arow + kt * 32 + quad * 8);
#pragma unroll
    for (int nt = 0; nt < NT; ++nt){
      s16x8 b = *(const s16x8*)(Brow + nt * 16 * bstride + kt * 32 + quad * 8);
      acc[nt] = __builtin_amdgcn_mfma_f32_16x16x32_bf16(a, b, acc[nt], 0, 0, 0);
    }
  }
}

// One downsample scale: conv(k,stride=k) -> TriU(a) -> hardswish -> TriU(b) -> out.
// Processed in two halves of 64 output channels.
template<int K_, int TD, int SW, int NTC, int KTC, int NT2, int KT2>
__device__ __forceinline__ void conv_scale(
    const unsigned short* xs, unsigned short* wk,
    const unsigned short* Wr, const unsigned short* Wma, const unsigned short* Wmb,
    const float* cbias, const float* ba, const float* bb,
    float* outb, int outoff, int wv, int m16, int quad){
  const int k = K_ / 128;
  unsigned short* wkA = wk;
  unsigned short* wkB = wk + 64 * SW;
#pragma unroll 1
  for (int half = 0; half < 2; ++half){
    int chalf = half * 64;
    int cb0 = chalf + wv * 16;
    // ---- conv as GEMM: hc[c_out][j] = sum_kk Wr[c_out][kk] * x[j*k+dt][ci] ----
    float bias0 = cbias[cb0 + quad * 4 + 0];
    float bias1 = cbias[cb0 + quad * 4 + 1];
    float bias2 = cbias[cb0 + quad * 4 + 2];
    float bias3 = cbias[cb0 + quad * 4 + 3];
    f32x4 acc[NTC];
#pragma unroll
    for (int nt = 0; nt < NTC; ++nt){
      acc[nt][0] = bias0; acc[nt][1] = bias1; acc[nt][2] = bias2; acc[nt][3] = bias3;
    }
    const unsigned short* Arow = Wr + (cb0 + m16) * K_;
#pragma unroll
    for (int kt = 0; kt < KTC; ++kt){
      const int kk = kt * 32;
      const int dt = kk >> 7, ci = kk & 127;
      s16x8 a = *(const s16x8*)(Arow + kk + quad * 8);
#pragma unroll
      for (int nt = 0; nt < NTC; ++nt){
        int j = nt * 16 + m16;
        s16x8 b = *(const s16x8*)(xs + (j * k + dt) * XS_STRIDE + ci + quad * 8);
        acc[nt] = __builtin_amdgcn_mfma_f32_16x16x32_bf16(a, b, acc[nt], 0, 0, 0);
      }
    }
#pragma unroll
    for (int nt = 0; nt < NTC; ++nt){
      int j = nt * 16 + m16;
#pragma unroll
      for (int r = 0; r < 4; ++r)
        wkA[(wv * 16 + quad * 4 + r) * SW + j] = f2bf(acc[nt][r]);
    }
    __syncthreads();
    // ---- TriU a + hardswish ----
    f32x4 t1[NT2];
#pragma unroll
    for (int nt = 0; nt < NT2; ++nt){
      float bj = ba[nt * 16 + m16];
      t1[nt][0] = bj; t1[nt][1] = bj; t1[nt][2] = bj; t1[nt][3] = bj;
    }
    mm_lds_a<NT2, KT2>(wkA + (wv * 16 + m16) * SW, Wma + m16 * TD, TD, t1, quad);
#pragma unroll
    for (int nt = 0; nt < NT2; ++nt){
      int j = nt * 16 + m16;
#pragma unroll
      for (int r = 0; r < 4; ++r)
        wkB[(wv * 16 + quad * 4 + r) * SW + j] = f2bf(hswish(t1[nt][r]));
    }
    __syncthreads();
    // ---- TriU b -> global ----
    f32x4 t2[NT2];
#pragma unroll
    for (int nt = 0; nt < NT2; ++nt){
      float bj = bb[nt * 16 + m16];
      t2[nt][0] = bj; t2[nt][1] = bj; t2[nt][2] = bj; t2[nt][3] = bj;
    }
    mm_lds_a<NT2, KT2>(wkB + (wv * 16 + m16) * SW, Wmb + m16 * TD, TD, t2, quad);
#pragma unroll
    for (int nt = 0; nt < NT2; ++nt){
      int j = nt * 16 + m16;
      *(f32x4*)(outb + (size_t)(outoff + j) * 128 + chalf + wv * 16 + quad * 4) = t2[nt];
    }
    __syncthreads();
  }
}

// ---- weight prep: mask tril, bf16-cast, permute conv weights to (c_out, dt, c_in) ----
__global__ void msmix_prep(const float* __restrict__ W0a, const float* __restrict__ W0b,
                           const float* __restrict__ c1w, const float* __restrict__ c2w,
                           const float* __restrict__ W1a, const float* __restrict__ W1b,
                           const float* __restrict__ W2a, const float* __restrict__ W2b,
                           unsigned short* __restrict__ ws){
  int i = blockIdx.x * 256 + threadIdx.x;
  if (i < 16384){ int j = i >> 7, c = i & 127; ws[i] = (c <= j) ? f2bf(W0a[i]) : 0; return; }
  i -= 16384;
  if (i < 16384){ int j = i >> 7, c = i & 127; ws[16384 + i] = (c <= j) ? f2bf(W0b[i]) : 0; return; }
  i -= 16384;
  if (i < 32768){ int co = i >> 8, rem = i & 255, dt = rem >> 7, ci = rem & 127;
    ws[32768 + i] = f2bf(c1w[co * 256 + ci * 2 + dt]); return; }
  i -= 32768;
  if (i < 65536){ int co = i >> 9, rem = i & 511, dt = rem >> 7, ci = rem & 127;
    ws[65536 + i] = f2bf(c2w[co * 512 + ci * 4 + dt]); return; }
  i -= 65536;
  if (i < 4096){ int j = i >> 6, t = i & 63; ws[131072 + i] = (t <= j) ? f2bf(W1a[i]) : 0; return; }
  i -= 4096;
  if (i < 4096){ int j = i >> 6, t = i & 63; ws[135168 + i] = (t <= j) ? f2bf(W1b[i]) : 0; return; }
  i -= 4096;
  if (i < 1024){ int j = i >> 5, t = i & 31; ws[139264 + i] = (t <= j) ? f2bf(W2a[i]) : 0; return; }
  i -= 1024;
  if (i < 1024){ int j = i >> 5, t = i & 31; ws[140288 + i] = (t <= j) ? f2bf(W2b[i]) : 0; return; }
}

__global__ __launch_bounds__(256) void msmix_main(
    const float* __restrict__ x, const float* __restrict__ gamma, const float* __restrict__ beta,
    const float* __restrict__ b0a, const float* __restrict__ b0b,
    const float* __restrict__ c1b, const float* __restrict__ b1a, const float* __restrict__ b1b,
    const float* __restrict__ c2b, const float* __restrict__ b2a, const float* __restrict__ b2b,
    const unsigned short* __restrict__ wsw, float* __restrict__ out){
  __shared__ unsigned short xs[128 * XS_STRIDE];  // x[b] in bf16 (raw, later LN-affined in place)
  __shared__ unsigned short wk[9216];             // intermediate halves (h1s / hc / g1)
  __shared__ float red[10];

  const int tid = threadIdx.x;
  const int b = blockIdx.x;
  const int lane = tid & 63, wv = tid >> 6;
  const int m16 = lane & 15, quad = lane >> 4;
  const float* xb = x + (size_t)b * 16384;
  float* outb = out + (size_t)b * (224 * 128);

  // ---- phase 0: load x, stats, stash bf16 in LDS ----
  float s = 0.f, ss = 0.f;
#pragma unroll
  for (int it = 0; it < 16; ++it){
    int e = it * 1024 + tid * 4;
    float4 v = *(const float4*)(xb + e);
    s += v.x + v.y + v.z + v.w;
    ss += v.x * v.x + v.y * v.y + v.z * v.z + v.w * v.w;
    int t = e >> 7, c = e & 127;
    ushort4 u;
    u.x = f2bf(v.x); u.y = f2bf(v.y); u.z = f2bf(v.z); u.w = f2bf(v.w);
    *(ushort4*)&xs[t * XS_STRIDE + c] = u;
  }
#pragma unroll
  for (int off = 32; off; off >>= 1){
    s += __shfl_down(s, off);
    ss += __shfl_down(ss, off);
  }
  if (lane == 0){ red[wv] = s; red[4 + wv] = ss; }
  __syncthreads();
  if (tid == 0){
    float S = red[0] + red[1] + red[2] + red[3];
    float SS = red[4] + red[5] + red[6] + red[7];
    float mu = S * (1.f / 16384.f);
    float var = SS * (1.f / 16384.f) - mu * mu;
    red[8] = mu;
    red[9] = rsqrtf(var + 1e-5f);
  }
  __syncthreads();
  const float mu = red[8], rs = red[9];

  const unsigned short* Wm0a = wsw;
  const unsigned short* Wm0b = wsw + 16384;
  const unsigned short* Wr1  = wsw + 32768;
  const unsigned short* Wr2  = wsw + 65536;
  const unsigned short* Wm1a = wsw + 131072;
  const unsigned short* Wm1b = wsw + 135168;
  const unsigned short* Wm2a = wsw + 139264;
  const unsigned short* Wm2b = wsw + 140288;

  // ---- scales 1, 2 on raw x ----
  conv_scale<256, 64, 72, 4, 8, 4, 2>(xs, wk, Wr1, Wm1a, Wm1b, c1b, b1a, b1b,
                                      outb, 128, wv, m16, quad);
  conv_scale<512, 32, 40, 2, 16, 2, 1>(xs, wk, Wr2, Wm2a, Wm2b, c2b, b2a, b2b,
                                       outb, 192, wv, m16, quad);

  // ---- LN affine in place: xs = (xs - mu)*rs*gamma + beta ----
#pragma unroll 1
  for (int it = 0; it < 16; ++it){
    int e = it * 1024 + tid * 4;
    int t = e >> 7, c = e & 127;
    float4 g  = *(const float4*)(gamma + e);
    float4 be = *(const float4*)(beta + e);
    ushort4 u = *(ushort4*)&xs[t * XS_STRIDE + c];
    u.x = f2bf((bf2f(u.x) - mu) * rs * g.x + be.x);
    u.y = f2bf((bf2f(u.y) - mu) * rs * g.y + be.y);
    u.z = f2bf((bf2f(u.z) - mu) * rs * g.z + be.z);
    u.w = f2bf((bf2f(u.w) - mu) * rs * g.w + be.w);
    *(ushort4*)&xs[t * XS_STRIDE + c] = u;
  }
  __syncthreads();

  // ---- scale 0: h1 = hswish(hn @ tril(W0a)^T + b0a); h2 = h1 @ tril(W0b)^T + b0b;
  //      out[b][j][t] = h2[t][j]. Two halves of 64 t-rows. ----
#pragma unroll 1
  for (int hb = 0; hb < 128; hb += 64){
    f32x4 acc[8];
#pragma unroll
    for (int nt = 0; nt < 8; ++nt){
      float bj = b0a[nt * 16 + m16];
      acc[nt][0] = bj; acc[nt][1] = bj; acc[nt][2] = bj; acc[nt][3] = bj;
    }
    mm_lds_a<8, 4>(xs + (hb + wv * 16 + m16) * XS_STRIDE, Wm0a + m16 * 128, 128, acc, quad);
#pragma unroll
    for (int nt = 0; nt < 8; ++nt){
      int j = nt * 16 + m16;
#pragma unroll
      for (int r = 0; r < 4; ++r)
        wk[(wv * 16 + quad * 4 + r) * XS_STRIDE + j] = f2bf(hswish(acc[nt][r]));
    }
    __syncthreads();
    f32x4 a2[8];
#pragma unroll
    for (int nt = 0; nt < 8; ++nt){
      float bj = b0b[nt * 16 + m16];
      a2[nt][0] = bj; a2[nt][1] = bj; a2[nt][2] = bj; a2[nt][3] = bj;
    }
    mm_lds_a<8, 4>(wk + (wv * 16 + m16) * XS_STRIDE, Wm0b + m16 * 128, 128, a2, quad);
#pragma unroll
    for (int nt = 0; nt < 8; ++nt){
      int j = nt * 16 + m16;
      *(f32x4*)(outb + (size_t)j * 128 + hb + wv * 16 + quad * 4) = a2[nt];
    }
    __syncthreads();
  }
}

extern "C" void kernel_launch(void* const* d_in, const int* in_sizes, int n_in,
                              void* d_out, int out_size, void* d_ws, size_t ws_size,
                              hipStream_t stream){
  const float* x    = (const float*)d_in[0];
  const float* gmm  = (const float*)d_in[1];
  const float* beta = (const float*)d_in[2];
  const float* W0a  = (const float*)d_in[3];
  const float* b0a  = (const float*)d_in[4];
  const float* W0b  = (const float*)d_in[5];
  const float* b0b  = (const float*)d_in[6];
  const float* c1w  = (const float*)d_in[7];
  const float* c1b  = (const float*)d_in[8];
  const float* W1a  = (const float*)d_in[9];
  const float* b1a  = (const float*)d_in[10];
  const float* W1b  = (const float*)d_in[11];
  const float* b1b  = (const float*)d_in[12];
  const float* c2w  = (const float*)d_in[13];
  const float* c2b  = (const float*)d_in[14];
  const float* W2a  = (const float*)d_in[15];
  const float* b2a  = (const float*)d_in[16];
  const float* W2b  = (const float*)d_in[17];
  const float* b2b  = (const float*)d_in[18];
  unsigned short* ws = (unsigned short*)d_ws;
  float* out = (float*)d_out;

  hipLaunchKernelGGL(msmix_prep, dim3(552), dim3(256), 0, stream,
                     W0a, W0b, c1w, c2w, W1a, W1b, W2a, W2b, ws);
  hipLaunchKernelGGL(msmix_main, dim3(2048), dim3(256), 0, stream,
                     x, gmm, beta, b0a, b0b, c1b, b1a, b1b, c2b, b2a, b2b, ws, out);
}

// Round 2
// 446.678 us; speedup vs baseline: 1.2673x; 1.2673x over previous
//
#include <hip/hip_runtime.h>

// MultiScaleTimeMixer: B=2048, T=128, C=128, scales {128, 64, 32}
// R2: two blocks per batch (type0 = LN+scale0, type12 = scales 1+2).
// Weights register-resident per wave (B-fragments); A-side from LDS.
// LDS 53.2 KB -> 3 blocks/CU; launch_bounds(256,3).

typedef __attribute__((ext_vector_type(8))) short s16x8;
typedef __attribute__((ext_vector_type(4))) float f32x4;

#define XSTR 136   // x tile stride (shorts): 272 B rows, 16B aligned
#define HCSTR 72   // scale1 work stride: 144 B rows
#define H2STR 40   // scale2 work stride: 80 B rows

__device__ __forceinline__ unsigned short f2bf(float f){
  unsigned int u = __float_as_uint(f);
  u += 0x7FFFu + ((u >> 16) & 1u);          // RNE
  return (unsigned short)(u >> 16);
}
__device__ __forceinline__ float hswish(float v){
  float c = fminf(fmaxf(v + 3.0f, 0.0f), 6.0f);
  return v * c * (1.0f / 6.0f);
}
#define MFMA(a, b, c) __builtin_amdgcn_mfma_f32_16x16x32_bf16((a), (b), (c), 0, 0, 0)

// ---- weight prep: mask tril, bf16-cast, permute conv weights to (c_out, dt, c_in) ----
__global__ void msmix_prep(const float* __restrict__ W0a, const float* __restrict__ W0b,
                           const float* __restrict__ c1w, const float* __restrict__ c2w,
                           const float* __restrict__ W1a, const float* __restrict__ W1b,
                           const float* __restrict__ W2a, const float* __restrict__ W2b,
                           unsigned short* __restrict__ ws){
  int i = blockIdx.x * 256 + threadIdx.x;
  if (i < 16384){ int j = i >> 7, c = i & 127; ws[i] = (c <= j) ? f2bf(W0a[i]) : 0; return; }
  i -= 16384;
  if (i < 16384){ int j = i >> 7, c = i & 127; ws[16384 + i] = (c <= j) ? f2bf(W0b[i]) : 0; return; }
  i -= 16384;
  if (i < 32768){ int co = i >> 8, rem = i & 255, dt = rem >> 7, ci = rem & 127;
    ws[32768 + i] = f2bf(c1w[co * 256 + ci * 2 + dt]); return; }
  i -= 32768;
  if (i < 65536){ int co = i >> 9, rem = i & 511, dt = rem >> 7, ci = rem & 127;
    ws[65536 + i] = f2bf(c2w[co * 512 + ci * 4 + dt]); return; }
  i -= 65536;
  if (i < 4096){ int j = i >> 6, t = i & 63; ws[131072 + i] = (t <= j) ? f2bf(W1a[i]) : 0; return; }
  i -= 4096;
  if (i < 4096){ int j = i >> 6, t = i & 63; ws[135168 + i] = (t <= j) ? f2bf(W1b[i]) : 0; return; }
  i -= 4096;
  if (i < 1024){ int j = i >> 5, t = i & 31; ws[139264 + i] = (t <= j) ? f2bf(W2a[i]) : 0; return; }
  i -= 1024;
  if (i < 1024){ int j = i >> 5, t = i & 31; ws[140288 + i] = (t <= j) ? f2bf(W2b[i]) : 0; return; }
}

__global__ __launch_bounds__(256, 3) void msmix_main(
    const float* __restrict__ x, const float* __restrict__ gamma, const float* __restrict__ beta,
    const float* __restrict__ b0a, const float* __restrict__ b0b,
    const float* __restrict__ c1b, const float* __restrict__ b1a, const float* __restrict__ b1b,
    const float* __restrict__ c2b, const float* __restrict__ b2a, const float* __restrict__ b2b,
    const unsigned short* __restrict__ wsw, float* __restrict__ out){
  __shared__ unsigned short smem[26624];   // 53248 B: xs[17408] + work[9216]
  __shared__ float red[10];

  const int tid = threadIdx.x;
  const int type = blockIdx.x & 1;
  const int b = blockIdx.x >> 1;
  const int lane = tid & 63, wv = tid >> 6;
  const int m16 = lane & 15, quad = lane >> 4;
  const float* xb = x + (size_t)b * 16384;
  float* outb = out + (size_t)b * (224 * 128);

  unsigned short* xs = smem;
  unsigned short* wkr = smem + 17408;   // 9216-short work region

  const unsigned short* Wm0a = wsw;
  const unsigned short* Wm0b = wsw + 16384;
  const unsigned short* Wr1  = wsw + 32768;
  const unsigned short* Wr2  = wsw + 65536;
  const unsigned short* Wm1a = wsw + 131072;
  const unsigned short* Wm1b = wsw + 135168;
  const unsigned short* Wm2a = wsw + 139264;
  const unsigned short* Wm2b = wsw + 140288;

  if (type == 0){
    // ================= scale 0: LN + two chained 128x128 GEMMs =================
    // phase 0: load x into regs, reduce stats
    float4 v[16];
    float s = 0.f, ss = 0.f;
#pragma unroll
    for (int it = 0; it < 16; ++it){
      v[it] = *(const float4*)(xb + it * 1024 + tid * 4);
      s  += v[it].x + v[it].y + v[it].z + v[it].w;
      ss += v[it].x * v[it].x + v[it].y * v[it].y + v[it].z * v[it].z + v[it].w * v[it].w;
    }
#pragma unroll
    for (int off = 32; off; off >>= 1){
      s += __shfl_down(s, off);
      ss += __shfl_down(ss, off);
    }
    if (lane == 0){ red[wv] = s; red[4 + wv] = ss; }
    __syncthreads();
    if (tid == 0){
      float S = red[0] + red[1] + red[2] + red[3];
      float SS = red[4] + red[5] + red[6] + red[7];
      float mu = S * (1.f / 16384.f);
      float var = SS * (1.f / 16384.f) - mu * mu;
      red[8] = mu;
      red[9] = rsqrtf(var + 1e-5f);
    }
    __syncthreads();
    const float mu = red[8], rs = red[9];
    // LN affine from registers -> bf16 LDS
#pragma unroll
    for (int it = 0; it < 16; ++it){
      int e = it * 1024 + tid * 4;
      int t = e >> 7, c = e & 127;
      float4 g  = *(const float4*)(gamma + e);
      float4 be = *(const float4*)(beta + e);
      ushort4 u;
      u.x = f2bf((v[it].x - mu) * rs * g.x + be.x);
      u.y = f2bf((v[it].y - mu) * rs * g.y + be.y);
      u.z = f2bf((v[it].z - mu) * rs * g.z + be.z);
      u.w = f2bf((v[it].w - mu) * rs * g.w + be.w);
      *(ushort4*)&xs[t * XSTR + c] = u;
    }
    __syncthreads();

    // register-resident weight strips: wave owns j-columns [wv*32, wv*32+32)
    s16x8 wa[2][4], wb[2][4];
#pragma unroll
    for (int nt = 0; nt < 2; ++nt){
      int j = wv * 32 + nt * 16 + m16;
#pragma unroll
      for (int kt = 0; kt < 4; ++kt){
        wa[nt][kt] = *(const s16x8*)(Wm0a + j * 128 + kt * 32 + quad * 8);
        wb[nt][kt] = *(const s16x8*)(Wm0b + j * 128 + kt * 32 + quad * 8);
      }
    }
    float bja[2] = { b0a[wv * 32 + m16], b0a[wv * 32 + 16 + m16] };
    float bjb[2] = { b0b[wv * 32 + m16], b0b[wv * 32 + 16 + m16] };
    unsigned short* h1 = wkr;   // 64 x XSTR half-tile

#pragma unroll 1
    for (int hb = 0; hb < 128; hb += 64){
      // GEMM1: h1[t][j] = hn[t][:] . W0a[j][:] + b0a[j], hswish
      f32x4 acc[4][2];
#pragma unroll
      for (int mt = 0; mt < 4; ++mt)
#pragma unroll
        for (int nt = 0; nt < 2; ++nt){
          acc[mt][nt][0] = bja[nt]; acc[mt][nt][1] = bja[nt];
          acc[mt][nt][2] = bja[nt]; acc[mt][nt][3] = bja[nt];
        }
#pragma unroll
      for (int kt = 0; kt < 4; ++kt)
#pragma unroll
        for (int mt = 0; mt < 4; ++mt){
          s16x8 a = *(const s16x8*)(xs + (hb + mt * 16 + m16) * XSTR + kt * 32 + quad * 8);
          acc[mt][0] = MFMA(a, wa[0][kt], acc[mt][0]);
          acc[mt][1] = MFMA(a, wa[1][kt], acc[mt][1]);
        }
#pragma unroll
      for (int mt = 0; mt < 4; ++mt)
#pragma unroll
        for (int nt = 0; nt < 2; ++nt)
#pragma unroll
          for (int r = 0; r < 4; ++r)
            h1[(mt * 16 + quad * 4 + r) * XSTR + wv * 32 + nt * 16 + m16] =
                f2bf(hswish(acc[mt][nt][r]));
      __syncthreads();
      // GEMM2: h2[t][j'] = h1[t][:] . W0b[j'][:] + b0b[j'] -> out[b][j'][t]
      f32x4 a2[4][2];
#pragma unroll
      for (int mt = 0; mt < 4; ++mt)
#pragma unroll
        for (int nt = 0; nt < 2; ++nt){
          a2[mt][nt][0] = bjb[nt]; a2[mt][nt][1] = bjb[nt];
          a2[mt][nt][2] = bjb[nt]; a2[mt][nt][3] = bjb[nt];
        }
#pragma unroll
      for (int kt = 0; kt < 4; ++kt)
#pragma unroll
        for (int mt = 0; mt < 4; ++mt){
          s16x8 a = *(const s16x8*)(h1 + (mt * 16 + m16) * XSTR + kt * 32 + quad * 8);
          a2[mt][0] = MFMA(a, wb[0][kt], a2[mt][0]);
          a2[mt][1] = MFMA(a, wb[1][kt], a2[mt][1]);
        }
#pragma unroll
      for (int mt = 0; mt < 4; ++mt)
#pragma unroll
        for (int nt = 0; nt < 2; ++nt)
          *(f32x4*)(outb + (size_t)(wv * 32 + nt * 16 + m16) * 128 + hb + mt * 16 + quad * 4) =
              a2[mt][nt];
      __syncthreads();
    }
  } else {
    // ================= scales 1 + 2 on raw x =================
    // phase 0: load x -> bf16 LDS (no stats)
#pragma unroll
    for (int it = 0; it < 16; ++it){
      int e = it * 1024 + tid * 4;
      int t = e >> 7, c = e & 127;
      float4 vv = *(const float4*)(xb + e);
      ushort4 u;
      u.x = f2bf(vv.x); u.y = f2bf(vv.y); u.z = f2bf(vv.z); u.w = f2bf(vv.w);
      *(ushort4*)&xs[t * XSTR + c] = u;
    }
    __syncthreads();

    // ---- scale 1 (td=64, conv k=2, K=256), two c_out halves of 64 ----
    {
      s16x8 wta[4][2], wtb[4][2];
#pragma unroll
      for (int nt = 0; nt < 4; ++nt)
#pragma unroll
        for (int kt = 0; kt < 2; ++kt){
          wta[nt][kt] = *(const s16x8*)(Wm1a + (nt * 16 + m16) * 64 + kt * 32 + quad * 8);
          wtb[nt][kt] = *(const s16x8*)(Wm1b + (nt * 16 + m16) * 64 + kt * 32 + quad * 8);
        }
      unsigned short* hc = wkr;
      unsigned short* g1 = wkr + 4608;
#pragma unroll 1
      for (int ch = 0; ch < 128; ch += 64){
        const int cg = ch + wv * 16 + m16;    // this wave's c_out rows (strip of 16)
        // conv GEMM: D[j][c_out], wave owns c_out strip 16
        s16x8 wr[8];
#pragma unroll
        for (int kt = 0; kt < 8; ++kt)
          wr[kt] = *(const s16x8*)(Wr1 + cg * 256 + kt * 32 + quad * 8);
        float cb = c1b[cg];
        f32x4 acc[4];
#pragma unroll
        for (int mt = 0; mt < 4; ++mt){
          acc[mt][0] = cb; acc[mt][1] = cb; acc[mt][2] = cb; acc[mt][3] = cb;
        }
#pragma unroll
        for (int kt = 0; kt < 8; ++kt){
          int kk = kt * 32 + quad * 8, dt = kk >> 7, ci = kk & 127;
#pragma unroll
          for (int mt = 0; mt < 4; ++mt){
            s16x8 a = *(const s16x8*)(xs + ((mt * 16 + m16) * 2 + dt) * XSTR + ci);
            acc[mt] = MFMA(a, wr[kt], acc[mt]);
          }
        }
        // epilogue -> hc[c_local][j] (ushort4 packed: j contiguous in r)
#pragma unroll
        for (int mt = 0; mt < 4; ++mt){
          ushort4 u;
          u.x = f2bf(acc[mt][0]); u.y = f2bf(acc[mt][1]);
          u.z = f2bf(acc[mt][2]); u.w = f2bf(acc[mt][3]);
          *(ushort4*)&hc[(wv * 16 + m16) * HCSTR + mt * 16 + quad * 4] = u;
        }
        __syncthreads();
        // TriU a + hswish
        f32x4 t1[4];
#pragma unroll
        for (int nt = 0; nt < 4; ++nt){
          float bj = b1a[nt * 16 + m16];
          t1[nt][0] = bj; t1[nt][1] = bj; t1[nt][2] = bj; t1[nt][3] = bj;
        }
#pragma unroll
        for (int kt = 0; kt < 2; ++kt){
          s16x8 a = *(const s16x8*)(hc + (wv * 16 + m16) * HCSTR + kt * 32 + quad * 8);
#pragma unroll
          for (int nt = 0; nt < 4; ++nt) t1[nt] = MFMA(a, wta[nt][kt], t1[nt]);
        }
#pragma unroll
        for (int nt = 0; nt < 4; ++nt)
#pragma unroll
          for (int r = 0; r < 4; ++r)
            g1[(wv * 16 + quad * 4 + r) * HCSTR + nt * 16 + m16] = f2bf(hswish(t1[nt][r]));
        __syncthreads();
        // TriU b -> out[b][128 + j'][c]
        f32x4 t2[4];
#pragma unroll
        for (int nt = 0; nt < 4; ++nt){
          float bj = b1b[nt * 16 + m16];
          t2[nt][0] = bj; t2[nt][1] = bj; t2[nt][2] = bj; t2[nt][3] = bj;
        }
#pragma unroll
        for (int kt = 0; kt < 2; ++kt){
          s16x8 a = *(const s16x8*)(g1 + (wv * 16 + m16) * HCSTR + kt * 32 + quad * 8);
#pragma unroll
          for (int nt = 0; nt < 4; ++nt) t2[nt] = MFMA(a, wtb[nt][kt], t2[nt]);
        }
#pragma unroll
        for (int nt = 0; nt < 4; ++nt)
          *(f32x4*)(outb + (size_t)(128 + nt * 16 + m16) * 128 + ch + wv * 16 + quad * 4) = t2[nt];
        __syncthreads();
      }
    }

    // ---- scale 2 (td=32, conv k=4, K=512), two c_out halves of 64 ----
    {
      s16x8 w2a[2], w2b[2];
#pragma unroll
      for (int nt = 0; nt < 2; ++nt){
        w2a[nt] = *(const s16x8*)(Wm2a + (nt * 16 + m16) * 32 + quad * 8);
        w2b[nt] = *(const s16x8*)(Wm2b + (nt * 16 + m16) * 32 + quad * 8);
      }
      unsigned short* hc = wkr;
      unsigned short* g2 = wkr + 2560;
#pragma unroll 1
      for (int ch = 0; ch < 128; ch += 64){
        const int cg = ch + wv * 16 + m16;
        float cb = c2b[cg];
        f32x4 acc[2];
#pragma unroll
        for (int mt = 0; mt < 2; ++mt){
          acc[mt][0] = cb; acc[mt][1] = cb; acc[mt][2] = cb; acc[mt][3] = cb;
        }
        // conv GEMM K=512: B-frags streamed from L2 (Wr2 = 128 KB, hot)
#pragma unroll
        for (int kt = 0; kt < 16; ++kt){
          int kk = kt * 32 + quad * 8, dt = kk >> 7, ci = kk & 127;
          s16x8 bf = *(const s16x8*)(Wr2 + cg * 512 + kk);
#pragma unroll
          for (int mt = 0; mt < 2; ++mt){
            s16x8 a = *(const s16x8*)(xs + ((mt * 16 + m16) * 4 + dt) * XSTR + ci);
            acc[mt] = MFMA(a, bf, acc[mt]);
          }
        }
#pragma unroll
        for (int mt = 0; mt < 2; ++mt){
          ushort4 u;
          u.x = f2bf(acc[mt][0]); u.y = f2bf(acc[mt][1]);
          u.z = f2bf(acc[mt][2]); u.w = f2bf(acc[mt][3]);
          *(ushort4*)&hc[(wv * 16 + m16) * H2STR + mt * 16 + quad * 4] = u;
        }
        __syncthreads();
        // TriU a + hswish
        f32x4 t1[2];
#pragma unroll
        for (int nt = 0; nt < 2; ++nt){
          float bj = b2a[nt * 16 + m16];
          t1[nt][0] = bj; t1[nt][1] = bj; t1[nt][2] = bj; t1[nt][3] = bj;
        }
        {
          s16x8 a = *(const s16x8*)(hc + (wv * 16 + m16) * H2STR + quad * 8);
#pragma unroll
          for (int nt = 0; nt < 2; ++nt) t1[nt] = MFMA(a, w2a[nt], t1[nt]);
        }
#pragma unroll
        for (int nt = 0; nt < 2; ++nt)
#pragma unroll
          for (int r = 0; r < 4; ++r)
            g2[(wv * 16 + quad * 4 + r) * H2STR + nt * 16 + m16] = f2bf(hswish(t1[nt][r]));
        __syncthreads();
        // TriU b -> out[b][192 + j'][c]
        f32x4 t2[2];
#pragma unroll
        for (int nt = 0; nt < 2; ++nt){
          float bj = b2b[nt * 16 + m16];
          t2[nt][0] = bj; t2[nt][1] = bj; t2[nt][2] = bj; t2[nt][3] = bj;
        }
        {
          s16x8 a = *(const s16x8*)(g2 + (wv * 16 + m16) * H2STR + quad * 8);
#pragma unroll
          for (int nt = 0; nt < 2; ++nt) t2[nt] = MFMA(a, w2b[nt], t2[nt]);
        }
#pragma unroll
        for (int nt = 0; nt < 2; ++nt)
          *(f32x4*)(outb + (size_t)(192 + nt * 16 + m16) * 128 + ch + wv * 16 + quad * 4) = t2[nt];
        __syncthreads();
      }
    }
  }
}

extern "C" void kernel_launch(void* const* d_in, const int* in_sizes, int n_in,
                              void* d_out, int out_size, void* d_ws, size_t ws_size,
                              hipStream_t stream){
  const float* x    = (const float*)d_in[0];
  const float* gmm  = (const float*)d_in[1];
  const float* beta = (const float*)d_in[2];
  const float* W0a  = (const float*)d_in[3];
  const float* b0a  = (const float*)d_in[4];
  const float* W0b  = (const float*)d_in[5];
  const float* b0b  = (const float*)d_in[6];
  const float* c1w  = (const float*)d_in[7];
  const float* c1b  = (const float*)d_in[8];
  const float* W1a  = (const float*)d_in[9];
  const float* b1a  = (const float*)d_in[10];
  const float* W1b  = (const float*)d_in[11];
  const float* b1b  = (const float*)d_in[12];
  const float* c2w  = (const float*)d_in[13];
  const float* c2b  = (const float*)d_in[14];
  const float* W2a  = (const float*)d_in[15];
  const float* b2a  = (const float*)d_in[16];
  const float* W2b  = (const float*)d_in[17];
  const float* b2b  = (const float*)d_in[18];
  unsigned short* ws = (unsigned short*)d_ws;
  float* out = (float*)d_out;

  hipLaunchKernelGGL(msmix_prep, dim3(552), dim3(256), 0, stream,
                     W0a, W0b, c1w, c2w, W1a, W1b, W2a, W2b, ws);
  hipLaunchKernelGGL(msmix_main, dim3(4096), dim3(256), 0, stream,
                     x, gmm, beta, b0a, b0b, c1b, b1a, b1b, c2b, b2a, b2b, ws, out);
}